// Round 4
// baseline (501.108 us; speedup 1.0000x reference)
//
#include <hip/hip_runtime.h>
#include <hip/hip_bf16.h>

typedef __attribute__((ext_vector_type(4))) float f32x4;
typedef __attribute__((ext_vector_type(8))) short s16x8;
typedef __attribute__((address_space(3))) unsigned int lds_uint;
typedef __attribute__((address_space(1))) const unsigned int g_uint;

static __device__ __forceinline__ unsigned short f2b(float f) {
    union { __hip_bfloat16 h; unsigned short u; } c;
    c.h = __float2bfloat16(f);
    return c.u;
}

static __device__ __forceinline__ void async_copy16(const void* gsrc, void* ldst) {
    __builtin_amdgcn_global_load_lds((g_uint*)gsrc, (lds_uint*)ldst, 16, 0, 0);
}

// ---------------- x fp32 -> bf16 ----------------
__global__ __launch_bounds__(256) void cvt_x_kernel(const float* __restrict__ x,
                                                    unsigned short* __restrict__ xb) {
    long i = ((long)blockIdx.x * 256 + threadIdx.x) * 8;
    float4 a = *(const float4*)(x + i);
    float4 b = *(const float4*)(x + i + 4);
    union { unsigned short s[8]; s16x8 v; } o;
    o.s[0] = f2b(a.x); o.s[1] = f2b(a.y); o.s[2] = f2b(a.z); o.s[3] = f2b(a.w);
    o.s[4] = f2b(b.x); o.s[5] = f2b(b.y); o.s[6] = f2b(b.z); o.s[7] = f2b(b.w);
    *(s16x8*)(xb + i) = o.v;
}

// ---------------- W [K,N] fp32 -> Wt [N,K] bf16 (transpose+convert) ----------------
__global__ __launch_bounds__(256) void cvt_wT_kernel(const float* __restrict__ W,
                                                     unsigned short* __restrict__ Wt,
                                                     int K, int N) {
    __shared__ float T[64][65];
    int nbk = K >> 6;
    int bk = blockIdx.x % nbk;
    int bn = blockIdx.x / nbk;
    int t = threadIdx.x;
    int r = t >> 4, c4 = (t & 15) << 2;
#pragma unroll
    for (int rd = 0; rd < 4; ++rd) {
        int row = rd * 16 + r;
        float4 v = *(const float4*)(W + (long)(bk * 64 + row) * N + bn * 64 + c4);
        T[row][c4 + 0] = v.x; T[row][c4 + 1] = v.y;
        T[row][c4 + 2] = v.z; T[row][c4 + 3] = v.w;
    }
    __syncthreads();
#pragma unroll
    for (int rd = 0; rd < 4; ++rd) {
        int nrow = rd * 16 + r;
        union { unsigned short s[4]; unsigned long long u; } o;
#pragma unroll
        for (int j = 0; j < 4; ++j) o.s[j] = f2b(T[c4 + j][nrow]);
        *(unsigned long long*)(Wt + (long)(bn * 64 + nrow) * K + bk * 64 + c4) = o.u;
    }
}

// ---------------- QKV GEMM: qkv = x @ Wqkv^T + b ----------------
// Q,K columns (n<2048) -> qkb[16384][2048] row-major.
// V columns (n>=2048) -> vT[(b*16+h)*64 + hd][s]  (transposed per head)
__global__ __launch_bounds__(256) void gemm_qkv_kernel(const unsigned short* __restrict__ A,
                                                       const unsigned short* __restrict__ Bt,
                                                       const float* __restrict__ bias,
                                                       unsigned short* __restrict__ qkb,
                                                       unsigned short* __restrict__ vT) {
    const int K = 1024;
    __shared__ unsigned short As[128 * 32];
    __shared__ unsigned short Bs[128 * 32];
    const int tid = threadIdx.x;
    const int w = tid >> 6, l = tid & 63;
    const int c = l & 15, g = l >> 4;
    const int tm = blockIdx.x / 24, tn = blockIdx.x % 24;
    const long m0 = (long)tm << 7, n0 = (long)tn << 7;

    f32x4 acc[4][4];
#pragma unroll
    for (int i = 0; i < 4; ++i)
#pragma unroll
        for (int j = 0; j < 4; ++j) acc[i][j] = (f32x4){0.f, 0.f, 0.f, 0.f};

    const int arow = tid >> 2, ac8 = (tid & 3) << 3;
    for (int k0 = 0; k0 < K; k0 += 32) {
        __syncthreads();
#pragma unroll
        for (int rd = 0; rd < 2; ++rd) {
            int row = arow + rd * 64;
            int off = (rd * 256 + tid) * 16;
            async_copy16(A + (m0 + row) * (long)K + k0 + ac8, (char*)As + off);
            async_copy16(Bt + (n0 + row) * (long)K + k0 + ac8, (char*)Bs + off);
        }
        __syncthreads();
        s16x8 af[4], bf_[4];
#pragma unroll
        for (int i = 0; i < 4; ++i) {
            af[i]  = *(const s16x8*)((const char*)As + ((w >> 1) * 64 + i * 16 + c) * 64 + g * 16);
            bf_[i] = *(const s16x8*)((const char*)Bs + ((w & 1) * 64 + i * 16 + c) * 64 + g * 16);
        }
#pragma unroll
        for (int i = 0; i < 4; ++i)
#pragma unroll
            for (int j = 0; j < 4; ++j)
                acc[i][j] = __builtin_amdgcn_mfma_f32_16x16x32_bf16(af[i], bf_[j], acc[i][j], 0, 0, 0);
    }

    if (n0 < 2048) {
#pragma unroll
        for (int j = 0; j < 4; ++j) {
            int n = (int)n0 + (w & 1) * 64 + j * 16 + c;
            float bv = bias[n];
#pragma unroll
            for (int i = 0; i < 4; ++i)
#pragma unroll
                for (int r = 0; r < 4; ++r) {
                    long m = m0 + (w >> 1) * 64 + i * 16 + 4 * g + r;
                    qkb[m * 2048 + n] = f2b(acc[i][j][r] + bv);
                }
        }
    } else {
#pragma unroll
        for (int j = 0; j < 4; ++j) {
            int n = (int)n0 + (w & 1) * 64 + j * 16 + c;
            float bv = bias[n];
            int h = (n - 2048) >> 6, hd = n & 63;
#pragma unroll
            for (int i = 0; i < 4; ++i) {
                long m = m0 + (w >> 1) * 64 + i * 16 + 4 * g;  // r=0; r=0..3 consecutive in s
                long bb = m >> 13;
                long s = m & 8191;
                union { unsigned short sh[4]; unsigned long long u; } o;
#pragma unroll
                for (int r = 0; r < 4; ++r) o.sh[r] = f2b(acc[i][j][r] + bv);
                *(unsigned long long*)(vT + ((bb * 16 + h) * 64 + hd) * 8192 + s) = o.u;
            }
        }
    }
}

// ---------------- out GEMM: C[M,N] fp32 = A[M,K]bf16 @ Bt[N,K]^T + bias ----------------
__global__ __launch_bounds__(256) void gemm_out_kernel(const unsigned short* __restrict__ A,
                                                       const unsigned short* __restrict__ Bt,
                                                       const float* __restrict__ bias,
                                                       float* __restrict__ C,
                                                       int M, int N, int K) {
    __shared__ unsigned short As[128 * 32];
    __shared__ unsigned short Bs[128 * 32];
    const int tid = threadIdx.x;
    const int w = tid >> 6, l = tid & 63;
    const int c = l & 15, g = l >> 4;
    const int ntile = N >> 7;
    const int tm = blockIdx.x / ntile, tn = blockIdx.x % ntile;
    const long m0 = (long)tm << 7, n0 = (long)tn << 7;

    f32x4 acc[4][4];
#pragma unroll
    for (int i = 0; i < 4; ++i)
#pragma unroll
        for (int j = 0; j < 4; ++j) acc[i][j] = (f32x4){0.f, 0.f, 0.f, 0.f};

    const int arow = tid >> 2, ac8 = (tid & 3) << 3;
    for (int k0 = 0; k0 < K; k0 += 32) {
        __syncthreads();
#pragma unroll
        for (int rd = 0; rd < 2; ++rd) {
            int row = arow + rd * 64;
            int off = (rd * 256 + tid) * 16;
            async_copy16(A + (m0 + row) * (long)K + k0 + ac8, (char*)As + off);
            async_copy16(Bt + (n0 + row) * (long)K + k0 + ac8, (char*)Bs + off);
        }
        __syncthreads();
        s16x8 af[4], bf_[4];
#pragma unroll
        for (int i = 0; i < 4; ++i) {
            af[i]  = *(const s16x8*)((const char*)As + ((w >> 1) * 64 + i * 16 + c) * 64 + g * 16);
            bf_[i] = *(const s16x8*)((const char*)Bs + ((w & 1) * 64 + i * 16 + c) * 64 + g * 16);
        }
#pragma unroll
        for (int i = 0; i < 4; ++i)
#pragma unroll
            for (int j = 0; j < 4; ++j)
                acc[i][j] = __builtin_amdgcn_mfma_f32_16x16x32_bf16(af[i], bf_[j], acc[i][j], 0, 0, 0);
    }
    // d_out is FLOAT32 (reference output dtype) — store fp32.
#pragma unroll
    for (int j = 0; j < 4; ++j) {
        int n = (int)n0 + (w & 1) * 64 + j * 16 + c;
        float bv = bias[n];
#pragma unroll
        for (int i = 0; i < 4; ++i)
#pragma unroll
            for (int r = 0; r < 4; ++r) {
                long m = m0 + (w >> 1) * 64 + i * 16 + 4 * g + r;
                C[m * (long)N + n] = acc[i][j][r] + bv;
            }
    }
}

// ---------------- ring block attention ----------------
// qkb: [B*S, 2048] bf16 (Q|K, head h at col h*64 / 1024+h*64)
// vT : [(b*16+h)*64 + hd][8192] bf16 (V transposed per head)
// out: [B*S, 1024] bf16
__global__ __launch_bounds__(256) void attn_kernel(const unsigned short* __restrict__ qkb,
                                                   const unsigned short* __restrict__ vT,
                                                   unsigned short* __restrict__ outp) {
    __shared__ unsigned short Ks[64 * 72];    // K rows [key][d], padded stride 72
    __shared__ unsigned short VTs[64 * 72];   // V^T rows [hd][key], padded stride 72
    __shared__ unsigned short Pws[4][16 * 72];// per-wave P [q][key], padded stride 72
    const int bid = blockIdx.x;
    const int qt = bid & 7;
    const int nblk = (bid >> 3) & 15;
    const int h = (bid >> 7) & 15;
    const int b = bid >> 11;
    const int tid = threadIdx.x;
    const int w = tid >> 6, l = tid & 63;
    const int c = l & 15, g = l >> 4;

    const long qrow = (long)b * 8192 + nblk * 512 + qt * 64 + w * 16 + c;
    const unsigned short* qp = qkb + qrow * 2048 + h * 64;
    // Q as B-operand: lane (c,g) holds Q^T[d = g*8+j][q=c] (d+32 for qf1)
    const s16x8 qf0 = *(const s16x8*)(qp + g * 8);
    const s16x8 qf1 = *(const s16x8*)(qp + 32 + g * 8);

    char* pw = (char*)(&Pws[w][0]);
    const float C2 = 0.125f * 1.44269504088896f;  // scale * log2(e)

    float outv[16];
#pragma unroll
    for (int i = 0; i < 16; ++i) outv[i] = 0.f;

    const int cc = tid & 7;        // 16B chunk within row
    const int rbase = tid >> 3;    // row 0..31, +32 for rd=1

    for (int p = 0; p < 2; ++p) {
        const int kblk = (nblk + p) & 15;
        const unsigned short* Kg = qkb + ((long)b * 8192 + kblk * 512) * 2048 + 1024 + h * 64;
        const unsigned short* Vg = vT + ((long)(b * 16 + h) * 64) * 8192 + kblk * 512;

        f32x4 oac[4];
#pragma unroll
        for (int i = 0; i < 4; ++i) oac[i] = (f32x4){0.f, 0.f, 0.f, 0.f};
        float mrun = -1e30f, lrun = 0.f;

        for (int ch = 0; ch < 8; ++ch) {
            // stage K tile [64 keys][64 d] and V^T tile [64 hd][64 keys] via regs
            s16x8 kreg[2], vreg[2];
#pragma unroll
            for (int rd = 0; rd < 2; ++rd) {
                int row = rd * 32 + rbase;
                kreg[rd] = *(const s16x8*)(Kg + (long)(ch * 64 + row) * 2048 + cc * 8);
                vreg[rd] = *(const s16x8*)(Vg + (long)row * 8192 + ch * 64 + cc * 8);
            }
            __syncthreads();  // prior iteration's LDS reads complete
#pragma unroll
            for (int rd = 0; rd < 2; ++rd) {
                int row = rd * 32 + rbase;
                *(s16x8*)((char*)Ks + row * 144 + cc * 16) = kreg[rd];
                *(s16x8*)((char*)VTs + row * 144 + cc * 16) = vreg[rd];
            }
            __syncthreads();

            // S^T = K @ Q^T : lane (c,g) holds S^T[key = kt*16 + 4g + r][q = c]
            f32x4 sac[4];
#pragma unroll
            for (int i = 0; i < 4; ++i) sac[i] = (f32x4){0.f, 0.f, 0.f, 0.f};
#pragma unroll
            for (int kt = 0; kt < 4; ++kt) {
                const char* kr = (const char*)Ks + (kt * 16 + c) * 144;
                s16x8 a0 = *(const s16x8*)(kr + g * 16);
                s16x8 a1 = *(const s16x8*)(kr + 64 + g * 16);
                sac[kt] = __builtin_amdgcn_mfma_f32_16x16x32_bf16(a0, qf0, sac[kt], 0, 0, 0);
                sac[kt] = __builtin_amdgcn_mfma_f32_16x16x32_bf16(a1, qf1, sac[kt], 0, 0, 0);
            }

            // online softmax for q=c (keys spread over regs and the 4 g-lanes)
            float mx = sac[0][0];
#pragma unroll
            for (int kt = 0; kt < 4; ++kt)
#pragma unroll
                for (int r = 0; r < 4; ++r) mx = fmaxf(mx, sac[kt][r]);
            mx = fmaxf(mx, __shfl_xor(mx, 16, 64));
            mx = fmaxf(mx, __shfl_xor(mx, 32, 64));
            float mnew = fmaxf(mrun, mx);
            float alpha = exp2f((mrun - mnew) * C2);

            // P = exp(scale*(S-m)); write to wave-private LDS as [q][key]
            float ls = 0.f;
#pragma unroll
            for (int kt = 0; kt < 4; ++kt) {
                union { unsigned short sh[4]; unsigned long long u; } pk;
#pragma unroll
                for (int r = 0; r < 4; ++r) {
                    float e = exp2f((sac[kt][r] - mnew) * C2);
                    ls += e;
                    pk.sh[r] = f2b(e);
                }
                // row q=c, keys kt*16+4g .. +3
                *(unsigned long long*)(pw + c * 144 + kt * 32 + g * 8) = pk.u;
            }
            ls += __shfl_xor(ls, 16, 64);
            ls += __shfl_xor(ls, 32, 64);
            lrun = lrun * alpha + ls;
            mrun = mnew;
#pragma unroll
            for (int i = 0; i < 4; ++i) oac[i] *= alpha;

            // O^T += V^T @ P^T : A = V^T rows (hd), B = P^T (lane (c,g): P[c][kf*32+g*8+j])
#pragma unroll
            for (int kf = 0; kf < 2; ++kf) {
                s16x8 pf = *(const s16x8*)(pw + c * 144 + kf * 64 + g * 16);
#pragma unroll
                for (int ht = 0; ht < 4; ++ht) {
                    s16x8 vf = *(const s16x8*)((const char*)VTs + (ht * 16 + c) * 144 + kf * 64 + g * 16);
                    oac[ht] = __builtin_amdgcn_mfma_f32_16x16x32_bf16(vf, pf, oac[ht], 0, 0, 0);
                }
            }
        }  // chunks

        float inv = 1.f / lrun;
#pragma unroll
        for (int i = 0; i < 16; ++i) outv[i] += oac[i >> 2][i & 3] * inv;
    }  // passes

    // lane holds O^T[hd = ht*16 + 4g + r][q = c]; pack 4 consecutive hd per 8B store
    unsigned short* op = outp + qrow * 1024 + h * 64;
#pragma unroll
    for (int ht = 0; ht < 4; ++ht) {
        union { unsigned short sh[4]; unsigned long long u; } o;
#pragma unroll
        for (int r = 0; r < 4; ++r) o.sh[r] = f2b(outv[ht * 4 + r]);
        *(unsigned long long*)(op + ht * 16 + 4 * g) = o.u;
    }
}

extern "C" void kernel_launch(void* const* d_in, const int* in_sizes, int n_in,
                              void* d_out, int out_size, void* d_ws, size_t ws_size,
                              hipStream_t stream) {
    const float* x    = (const float*)d_in[0];
    const float* Wqkv = (const float*)d_in[1];
    const float* bqkv = (const float*)d_in[2];
    const float* Wout = (const float*)d_in[3];
    const float* bout = (const float*)d_in[4];
    float* out = (float*)d_out;  // reference output dtype is float32

    char* ws = (char*)d_ws;
    unsigned short* xbf   = (unsigned short*)ws;                    // [0, 32M)
    unsigned short* wqkvT = (unsigned short*)(ws + 33554432);       // [32M, 38M)
    unsigned short* woutT = (unsigned short*)(ws + 39845888);      // [38M, 40M)
    unsigned short* qkb   = (unsigned short*)(ws + 41943040);      // [40M, 104M)
    unsigned short* vT    = (unsigned short*)(ws + 109051904);     // [104M, 136M)
    unsigned short* attn  = xbf;  // alias: xbf dead after QKV GEMM

    cvt_x_kernel<<<8192, 256, 0, stream>>>(x, xbf);
    cvt_wT_kernel<<<(1024 / 64) * (3072 / 64), 256, 0, stream>>>(Wqkv, wqkvT, 1024, 3072);
    cvt_wT_kernel<<<(1024 / 64) * (1024 / 64), 256, 0, stream>>>(Wout, woutT, 1024, 1024);
    gemm_qkv_kernel<<<128 * 24, 256, 0, stream>>>(xbf, wqkvT, bqkv, qkb, vT);
    attn_kernel<<<4096, 256, 0, stream>>>(qkb, vT, attn);
    gemm_out_kernel<<<128 * 8, 256, 0, stream>>>(attn, woutT, bout, out, 16384, 1024, 1024);
}

// Round 5
// 487.517 us; speedup vs baseline: 1.0279x; 1.0279x over previous
//
#include <hip/hip_runtime.h>
#include <hip/hip_bf16.h>

typedef __attribute__((ext_vector_type(4))) float f32x4;
typedef __attribute__((ext_vector_type(8))) short s16x8;
typedef __attribute__((address_space(3))) unsigned int lds_uint;
typedef __attribute__((address_space(1))) const unsigned int g_uint;

static __device__ __forceinline__ unsigned short f2b(float f) {
    union { __hip_bfloat16 h; unsigned short u; } c;
    c.h = __float2bfloat16(f);
    return c.u;
}

static __device__ __forceinline__ void async_copy16(const void* gsrc, void* ldst) {
    __builtin_amdgcn_global_load_lds((g_uint*)gsrc, (lds_uint*)ldst, 16, 0, 0);
}

// ---------------- x fp32 -> bf16 ----------------
__global__ __launch_bounds__(256) void cvt_x_kernel(const float* __restrict__ x,
                                                    unsigned short* __restrict__ xb) {
    long i = ((long)blockIdx.x * 256 + threadIdx.x) * 8;
    float4 a = *(const float4*)(x + i);
    float4 b = *(const float4*)(x + i + 4);
    union { unsigned short s[8]; s16x8 v; } o;
    o.s[0] = f2b(a.x); o.s[1] = f2b(a.y); o.s[2] = f2b(a.z); o.s[3] = f2b(a.w);
    o.s[4] = f2b(b.x); o.s[5] = f2b(b.y); o.s[6] = f2b(b.z); o.s[7] = f2b(b.w);
    *(s16x8*)(xb + i) = o.v;
}

// ---------------- W [K,N] fp32 -> Wt [N,K] bf16 (transpose+convert) ----------------
__global__ __launch_bounds__(256) void cvt_wT_kernel(const float* __restrict__ W,
                                                     unsigned short* __restrict__ Wt,
                                                     int K, int N) {
    __shared__ float T[64][65];
    int nbk = K >> 6;
    int bk = blockIdx.x % nbk;
    int bn = blockIdx.x / nbk;
    int t = threadIdx.x;
    int r = t >> 4, c4 = (t & 15) << 2;
#pragma unroll
    for (int rd = 0; rd < 4; ++rd) {
        int row = rd * 16 + r;
        float4 v = *(const float4*)(W + (long)(bk * 64 + row) * N + bn * 64 + c4);
        T[row][c4 + 0] = v.x; T[row][c4 + 1] = v.y;
        T[row][c4 + 2] = v.z; T[row][c4 + 3] = v.w;
    }
    __syncthreads();
#pragma unroll
    for (int rd = 0; rd < 4; ++rd) {
        int nrow = rd * 16 + r;
        union { unsigned short s[4]; unsigned long long u; } o;
#pragma unroll
        for (int j = 0; j < 4; ++j) o.s[j] = f2b(T[c4 + j][nrow]);
        *(unsigned long long*)(Wt + (long)(bn * 64 + nrow) * K + bk * 64 + c4) = o.u;
    }
}

// ---------------- QKV GEMM: qkv = x @ Wqkv^T + b ----------------
// Q,K columns (n<2048) -> qkb[16384][2048] row-major.
// V columns (n>=2048) -> vT[(b*16+h)*64 + hd][s]  (transposed per head)
__global__ __launch_bounds__(256) void gemm_qkv_kernel(const unsigned short* __restrict__ A,
                                                       const unsigned short* __restrict__ Bt,
                                                       const float* __restrict__ bias,
                                                       unsigned short* __restrict__ qkb,
                                                       unsigned short* __restrict__ vT) {
    const int K = 1024;
    __shared__ unsigned short As[128 * 32];
    __shared__ unsigned short Bs[128 * 32];
    const int tid = threadIdx.x;
    const int w = tid >> 6, l = tid & 63;
    const int c = l & 15, g = l >> 4;
    const int wgid = (blockIdx.x & 7) * 384 + (blockIdx.x >> 3);  // XCD swizzle, 3072 wgs
    const int tm = wgid / 24, tn = wgid % 24;
    const long m0 = (long)tm << 7, n0 = (long)tn << 7;

    f32x4 acc[4][4];
#pragma unroll
    for (int i = 0; i < 4; ++i)
#pragma unroll
        for (int j = 0; j < 4; ++j) acc[i][j] = (f32x4){0.f, 0.f, 0.f, 0.f};

    const int arow = tid >> 2, ac8 = (tid & 3) << 3;
    for (int k0 = 0; k0 < K; k0 += 32) {
        __syncthreads();
#pragma unroll
        for (int rd = 0; rd < 2; ++rd) {
            int row = arow + rd * 64;
            int off = (rd * 256 + tid) * 16;
            async_copy16(A + (m0 + row) * (long)K + k0 + ac8, (char*)As + off);
            async_copy16(Bt + (n0 + row) * (long)K + k0 + ac8, (char*)Bs + off);
        }
        __syncthreads();
        s16x8 af[4], bf_[4];
#pragma unroll
        for (int i = 0; i < 4; ++i) {
            af[i]  = *(const s16x8*)((const char*)As + ((w >> 1) * 64 + i * 16 + c) * 64 + g * 16);
            bf_[i] = *(const s16x8*)((const char*)Bs + ((w & 1) * 64 + i * 16 + c) * 64 + g * 16);
        }
#pragma unroll
        for (int i = 0; i < 4; ++i)
#pragma unroll
            for (int j = 0; j < 4; ++j)
                acc[i][j] = __builtin_amdgcn_mfma_f32_16x16x32_bf16(af[i], bf_[j], acc[i][j], 0, 0, 0);
    }

    if (n0 < 2048) {
#pragma unroll
        for (int j = 0; j < 4; ++j) {
            int n = (int)n0 + (w & 1) * 64 + j * 16 + c;
            float bv = bias[n];
#pragma unroll
            for (int i = 0; i < 4; ++i)
#pragma unroll
                for (int r = 0; r < 4; ++r) {
                    long m = m0 + (w >> 1) * 64 + i * 16 + 4 * g + r;
                    qkb[m * 2048 + n] = f2b(acc[i][j][r] + bv);
                }
        }
    } else {
#pragma unroll
        for (int j = 0; j < 4; ++j) {
            int n = (int)n0 + (w & 1) * 64 + j * 16 + c;
            float bv = bias[n];
            int h = (n - 2048) >> 6, hd = n & 63;
#pragma unroll
            for (int i = 0; i < 4; ++i) {
                long m = m0 + (w >> 1) * 64 + i * 16 + 4 * g;  // r=0..3 consecutive in s
                long bb = m >> 13;
                long s = m & 8191;
                union { unsigned short sh[4]; unsigned long long u; } o;
#pragma unroll
                for (int r = 0; r < 4; ++r) o.sh[r] = f2b(acc[i][j][r] + bv);
                *(unsigned long long*)(vT + ((bb * 16 + h) * 64 + hd) * 8192 + s) = o.u;
            }
        }
    }
}

// ---------------- out GEMM: C[M,N] fp32 = A[M,K]bf16 @ Bt[N,K]^T + bias ----------------
__global__ __launch_bounds__(256) void gemm_out_kernel(const unsigned short* __restrict__ A,
                                                       const unsigned short* __restrict__ Bt,
                                                       const float* __restrict__ bias,
                                                       float* __restrict__ C,
                                                       int M, int N, int K) {
    __shared__ unsigned short As[128 * 32];
    __shared__ unsigned short Bs[128 * 32];
    const int tid = threadIdx.x;
    const int w = tid >> 6, l = tid & 63;
    const int c = l & 15, g = l >> 4;
    const int ntile = N >> 7;
    const int cpx = gridDim.x >> 3;
    const int wgid = (blockIdx.x & 7) * cpx + (blockIdx.x >> 3);  // XCD swizzle
    const int tm = wgid / ntile, tn = wgid % ntile;
    const long m0 = (long)tm << 7, n0 = (long)tn << 7;

    f32x4 acc[4][4];
#pragma unroll
    for (int i = 0; i < 4; ++i)
#pragma unroll
        for (int j = 0; j < 4; ++j) acc[i][j] = (f32x4){0.f, 0.f, 0.f, 0.f};

    const int arow = tid >> 2, ac8 = (tid & 3) << 3;
    for (int k0 = 0; k0 < K; k0 += 32) {
        __syncthreads();
#pragma unroll
        for (int rd = 0; rd < 2; ++rd) {
            int row = arow + rd * 64;
            int off = (rd * 256 + tid) * 16;
            async_copy16(A + (m0 + row) * (long)K + k0 + ac8, (char*)As + off);
            async_copy16(Bt + (n0 + row) * (long)K + k0 + ac8, (char*)Bs + off);
        }
        __syncthreads();
        s16x8 af[4], bf_[4];
#pragma unroll
        for (int i = 0; i < 4; ++i) {
            af[i]  = *(const s16x8*)((const char*)As + ((w >> 1) * 64 + i * 16 + c) * 64 + g * 16);
            bf_[i] = *(const s16x8*)((const char*)Bs + ((w & 1) * 64 + i * 16 + c) * 64 + g * 16);
        }
#pragma unroll
        for (int i = 0; i < 4; ++i)
#pragma unroll
            for (int j = 0; j < 4; ++j)
                acc[i][j] = __builtin_amdgcn_mfma_f32_16x16x32_bf16(af[i], bf_[j], acc[i][j], 0, 0, 0);
    }
#pragma unroll
    for (int j = 0; j < 4; ++j) {
        int n = (int)n0 + (w & 1) * 64 + j * 16 + c;
        float bv = bias[n];
#pragma unroll
        for (int i = 0; i < 4; ++i)
#pragma unroll
            for (int r = 0; r < 4; ++r) {
                long m = m0 + (w >> 1) * 64 + i * 16 + 4 * g + r;
                C[m * (long)N + n] = acc[i][j][r] + bv;
            }
    }
}

// ---------------- ring block attention (QBLK=128: 4 waves x 32 q-rows) ----------------
// qkb: [B*S, 2048] bf16 (Q|K, head h at col h*64 / 1024+h*64)
// vT : [(b*16+h)*64 + hd][8192] bf16 (V transposed per head)
// out: [B*S, 1024] bf16
__global__ __launch_bounds__(256) void attn_kernel(const unsigned short* __restrict__ qkb,
                                                   const unsigned short* __restrict__ vT,
                                                   unsigned short* __restrict__ outp) {
    __shared__ unsigned short Ks[64 * 72];     // K rows [key][d], padded stride 72
    __shared__ unsigned short VTs[64 * 72];    // V^T rows [hd][key], padded stride 72
    __shared__ unsigned short Pws[4][32 * 72]; // per-wave P [qg*16+q][key], padded stride 72
    const int bid = blockIdx.x;
    const int wgid = (bid & 7) * 256 + (bid >> 3);  // XCD swizzle (2048 wgs, 8 XCDs)
    const int qt = wgid & 3;
    const int nblk = (wgid >> 2) & 15;
    const int h = (wgid >> 6) & 15;
    const int b = wgid >> 10;
    const int tid = threadIdx.x;
    const int w = tid >> 6, l = tid & 63;
    const int c = l & 15, g = l >> 4;

    const long qrow0 = (long)b * 8192 + nblk * 512 + qt * 128 + w * 32 + c;
    // Q as B-operand: lane (c,g) holds Q^T[d = kf*32 + g*8 + j][q = c] per q-group
    s16x8 qf[2][2];
#pragma unroll
    for (int qg = 0; qg < 2; ++qg) {
        const unsigned short* qp = qkb + (qrow0 + qg * 16) * 2048 + h * 64;
        qf[qg][0] = *(const s16x8*)(qp + g * 8);
        qf[qg][1] = *(const s16x8*)(qp + 32 + g * 8);
    }

    char* pw = (char*)(&Pws[w][0]);
    const float C2 = 0.125f * 1.44269504088896f;  // scale * log2(e)

    const int cc = tid & 7;      // 16B chunk within row
    const int rbase = tid >> 3;  // row 0..31 (+32 for second)
    char* kwp = (char*)Ks + rbase * 144 + cc * 16;
    char* vwp = (char*)VTs + rbase * 144 + cc * 16;

    const int kb1 = (nblk + 1) & 15;
    const unsigned short* Kg0 = qkb + ((long)b * 8192 + nblk * 512) * 2048 + 1024 + h * 64
                                + (long)rbase * 2048 + cc * 8;
    const unsigned short* Kg1 = qkb + ((long)b * 8192 + kb1 * 512) * 2048 + 1024 + h * 64
                                + (long)rbase * 2048 + cc * 8;
    const unsigned short* Vg0 = vT + ((long)(b * 16 + h) * 64 + rbase) * 8192 + nblk * 512 + cc * 8;
    const unsigned short* Vg1 = vT + ((long)(b * 16 + h) * 64 + rbase) * 8192 + kb1 * 512 + cc * 8;

    float outv[2][16];
#pragma unroll
    for (int qg = 0; qg < 2; ++qg)
#pragma unroll
        for (int i = 0; i < 16; ++i) outv[qg][i] = 0.f;

    f32x4 oac[2][4];
#pragma unroll
    for (int qg = 0; qg < 2; ++qg)
#pragma unroll
        for (int i = 0; i < 4; ++i) oac[qg][i] = (f32x4){0.f, 0.f, 0.f, 0.f};
    float mrun[2] = {-3e38f, -3e38f}, lrun[2] = {0.f, 0.f};

    // prefetch chunk 0 of pass 0 (T14: issue-early / write-late)
    s16x8 kreg0 = *(const s16x8*)(Kg0);
    s16x8 kreg1 = *(const s16x8*)(Kg0 + 32 * 2048);
    s16x8 vreg0 = *(const s16x8*)(Vg0);
    s16x8 vreg1 = *(const s16x8*)(Vg0 + 32 * 8192);

    for (int it = 0; it < 16; ++it) {  // it = pass*8 + chunk
        __syncthreads();  // previous chunk's LDS reads complete
        *(s16x8*)(kwp) = kreg0;
        *(s16x8*)(kwp + 32 * 144) = kreg1;
        *(s16x8*)(vwp) = vreg0;
        *(s16x8*)(vwp + 32 * 144) = vreg1;
        {   // issue next-chunk global loads now; they fly during compute
            int itn = it + 1;
            const unsigned short* kn = ((itn & 8) ? Kg1 : Kg0) + ((itn & 7) << 17);  // chunk*64*2048
            const unsigned short* vn = ((itn & 8) ? Vg1 : Vg0) + ((itn & 7) << 6);   // chunk*64
            kreg0 = *(const s16x8*)(kn);
            kreg1 = *(const s16x8*)(kn + 32 * 2048);
            vreg0 = *(const s16x8*)(vn);
            vreg1 = *(const s16x8*)(vn + 32 * 8192);
        }
        __syncthreads();  // staged tile visible

        // S^T = K @ Q^T : lane (c,g) holds S^T[key = kt*16 + 4g + r][q = c] per qg
        f32x4 sac[2][4];
#pragma unroll
        for (int qg = 0; qg < 2; ++qg)
#pragma unroll
            for (int i = 0; i < 4; ++i) sac[qg][i] = (f32x4){0.f, 0.f, 0.f, 0.f};
#pragma unroll
        for (int kt = 0; kt < 4; ++kt) {
            const char* kr = (const char*)Ks + (kt * 16 + c) * 144 + g * 16;
            s16x8 a0 = *(const s16x8*)(kr);
            s16x8 a1 = *(const s16x8*)(kr + 64);
            sac[0][kt] = __builtin_amdgcn_mfma_f32_16x16x32_bf16(a0, qf[0][0], sac[0][kt], 0, 0, 0);
            sac[0][kt] = __builtin_amdgcn_mfma_f32_16x16x32_bf16(a1, qf[0][1], sac[0][kt], 0, 0, 0);
            sac[1][kt] = __builtin_amdgcn_mfma_f32_16x16x32_bf16(a0, qf[1][0], sac[1][kt], 0, 0, 0);
            sac[1][kt] = __builtin_amdgcn_mfma_f32_16x16x32_bf16(a1, qf[1][1], sac[1][kt], 0, 0, 0);
        }

        // online softmax per q-group; P -> wave-private LDS [qg*16+q][key]
#pragma unroll
        for (int qg = 0; qg < 2; ++qg) {
            float mx = sac[qg][0][0];
#pragma unroll
            for (int kt = 0; kt < 4; ++kt)
#pragma unroll
                for (int r = 0; r < 4; ++r) mx = fmaxf(mx, sac[qg][kt][r]);
            mx = fmaxf(mx, __shfl_xor(mx, 16, 64));
            mx = fmaxf(mx, __shfl_xor(mx, 32, 64));
            float mnew = fmaxf(mrun[qg], mx);
            float alpha = exp2f((mrun[qg] - mnew) * C2);
            float ls = 0.f;
#pragma unroll
            for (int kt = 0; kt < 4; ++kt) {
                union { unsigned short sh[4]; unsigned long long u; } pk;
#pragma unroll
                for (int r = 0; r < 4; ++r) {
                    float e = exp2f((sac[qg][kt][r] - mnew) * C2);
                    ls += e;
                    pk.sh[r] = f2b(e);
                }
                *(unsigned long long*)(pw + (qg * 16 + c) * 144 + kt * 32 + g * 8) = pk.u;
            }
            ls += __shfl_xor(ls, 16, 64);
            ls += __shfl_xor(ls, 32, 64);
            lrun[qg] = lrun[qg] * alpha + ls;
            mrun[qg] = mnew;
#pragma unroll
            for (int i = 0; i < 4; ++i) oac[qg][i] *= alpha;
        }

        // O^T += V^T @ P^T : A = V^T rows (hd), shared across qg; B = P^T per qg
#pragma unroll
        for (int kf = 0; kf < 2; ++kf) {
            s16x8 pf0 = *(const s16x8*)(pw + c * 144 + kf * 64 + g * 16);
            s16x8 pf1 = *(const s16x8*)(pw + (16 + c) * 144 + kf * 64 + g * 16);
#pragma unroll
            for (int ht = 0; ht < 4; ++ht) {
                s16x8 vf = *(const s16x8*)((const char*)VTs + (ht * 16 + c) * 144 + kf * 64 + g * 16);
                oac[0][ht] = __builtin_amdgcn_mfma_f32_16x16x32_bf16(vf, pf0, oac[0][ht], 0, 0, 0);
                oac[1][ht] = __builtin_amdgcn_mfma_f32_16x16x32_bf16(vf, pf1, oac[1][ht], 0, 0, 0);
            }
        }

        if ((it & 7) == 7) {  // pass boundary: fold normalized pass result, reset state
#pragma unroll
            for (int qg = 0; qg < 2; ++qg) {
                float inv = 1.f / lrun[qg];
#pragma unroll
                for (int i = 0; i < 16; ++i) outv[qg][i] += oac[qg][i >> 2][i & 3] * inv;
#pragma unroll
                for (int i = 0; i < 4; ++i) oac[qg][i] = (f32x4){0.f, 0.f, 0.f, 0.f};
                mrun[qg] = -3e38f;
                lrun[qg] = 0.f;
            }
        }
    }

    // lane holds O^T[hd = ht*16 + 4g + r][q = c] per qg; 8B packed stores
#pragma unroll
    for (int qg = 0; qg < 2; ++qg) {
        unsigned short* op = outp + (qrow0 + qg * 16) * 1024 + h * 64;
#pragma unroll
        for (int ht = 0; ht < 4; ++ht) {
            union { unsigned short sh[4]; unsigned long long u; } o;
#pragma unroll
            for (int r = 0; r < 4; ++r) o.sh[r] = f2b(outv[qg][ht * 4 + r]);
            *(unsigned long long*)(op + ht * 16 + 4 * g) = o.u;
        }
    }
}

extern "C" void kernel_launch(void* const* d_in, const int* in_sizes, int n_in,
                              void* d_out, int out_size, void* d_ws, size_t ws_size,
                              hipStream_t stream) {
    const float* x    = (const float*)d_in[0];
    const float* Wqkv = (const float*)d_in[1];
    const float* bqkv = (const float*)d_in[2];
    const float* Wout = (const float*)d_in[3];
    const float* bout = (const float*)d_in[4];
    float* out = (float*)d_out;  // reference output dtype is float32

    char* ws = (char*)d_ws;
    unsigned short* xbf   = (unsigned short*)ws;                    // [0, 32M)
    unsigned short* wqkvT = (unsigned short*)(ws + 33554432);       // [32M, 38M)
    unsigned short* woutT = (unsigned short*)(ws + 39845888);      // [38M, 40M)
    unsigned short* qkb   = (unsigned short*)(ws + 41943040);      // [40M, 104M)
    unsigned short* vT    = (unsigned short*)(ws + 109051904);     // [104M, 136M)
    unsigned short* attn  = xbf;  // alias: xbf dead after QKV GEMM

    cvt_x_kernel<<<8192, 256, 0, stream>>>(x, xbf);
    cvt_wT_kernel<<<(1024 / 64) * (3072 / 64), 256, 0, stream>>>(Wqkv, wqkvT, 1024, 3072);
    cvt_wT_kernel<<<(1024 / 64) * (1024 / 64), 256, 0, stream>>>(Wout, woutT, 1024, 1024);
    gemm_qkv_kernel<<<128 * 24, 256, 0, stream>>>(xbf, wqkvT, bqkv, qkb, vT);
    attn_kernel<<<2048, 256, 0, stream>>>(qkb, vT, attn);
    gemm_out_kernel<<<128 * 8, 256, 0, stream>>>(attn, woutT, bout, out, 16384, 1024, 1024);
}

// Round 6
// 452.179 us; speedup vs baseline: 1.1082x; 1.0781x over previous
//
#include <hip/hip_runtime.h>
#include <hip/hip_bf16.h>

typedef __attribute__((ext_vector_type(4))) float f32x4;
typedef __attribute__((ext_vector_type(8))) short s16x8;
typedef __attribute__((address_space(3))) unsigned int lds_uint;
typedef __attribute__((address_space(1))) const unsigned int g_uint;

static __device__ __forceinline__ unsigned short f2b(float f) {
    union { __hip_bfloat16 h; unsigned short u; } c;
    c.h = __float2bfloat16(f);
    return c.u;
}

static __device__ __forceinline__ void async_copy16(const void* gsrc, void* ldst) {
    __builtin_amdgcn_global_load_lds((g_uint*)gsrc, (lds_uint*)ldst, 16, 0, 0);
}

// ---------------- x fp32 -> bf16 ----------------
__global__ __launch_bounds__(256) void cvt_x_kernel(const float* __restrict__ x,
                                                    unsigned short* __restrict__ xb) {
    long i = ((long)blockIdx.x * 256 + threadIdx.x) * 8;
    float4 a = *(const float4*)(x + i);
    float4 b = *(const float4*)(x + i + 4);
    union { unsigned short s[8]; s16x8 v; } o;
    o.s[0] = f2b(a.x); o.s[1] = f2b(a.y); o.s[2] = f2b(a.z); o.s[3] = f2b(a.w);
    o.s[4] = f2b(b.x); o.s[5] = f2b(b.y); o.s[6] = f2b(b.z); o.s[7] = f2b(b.w);
    *(s16x8*)(xb + i) = o.v;
}

// ---------------- W [K,N] fp32 -> Wt [N,K] bf16 (transpose+convert) ----------------
__global__ __launch_bounds__(256) void cvt_wT_kernel(const float* __restrict__ W,
                                                     unsigned short* __restrict__ Wt,
                                                     int K, int N) {
    __shared__ float T[64][65];
    int nbk = K >> 6;
    int bk = blockIdx.x % nbk;
    int bn = blockIdx.x / nbk;
    int t = threadIdx.x;
    int r = t >> 4, c4 = (t & 15) << 2;
#pragma unroll
    for (int rd = 0; rd < 4; ++rd) {
        int row = rd * 16 + r;
        float4 v = *(const float4*)(W + (long)(bk * 64 + row) * N + bn * 64 + c4);
        T[row][c4 + 0] = v.x; T[row][c4 + 1] = v.y;
        T[row][c4 + 2] = v.z; T[row][c4 + 3] = v.w;
    }
    __syncthreads();
#pragma unroll
    for (int rd = 0; rd < 4; ++rd) {
        int nrow = rd * 16 + r;
        union { unsigned short s[4]; unsigned long long u; } o;
#pragma unroll
        for (int j = 0; j < 4; ++j) o.s[j] = f2b(T[c4 + j][nrow]);
        *(unsigned long long*)(Wt + (long)(bn * 64 + nrow) * K + bk * 64 + c4) = o.u;
    }
}

// ---------------- 8-phase 256x256 GEMM, K=1024, B^T form ----------------
// OM=0: QKV epilogue (bf16 -> qkb cols<2048, vT transposed scatter for V)
// OM=1: fp32 out epilogue (N=1024)
// LDS: A bufs at [0,64K): block (buf*2+kh)*16K; B at [64K,128K). Block = [256 rows][32 k] bf16.
// Swizzle: lds[row][chunk] holds global chunk (chunk ^ ((row>>1)&3)); reads XOR the same.
template<int OM>
__global__ __launch_bounds__(512) void gemm256_kernel(const unsigned short* __restrict__ A,
                                                      const unsigned short* __restrict__ Bt,
                                                      const float* __restrict__ bias,
                                                      unsigned short* __restrict__ qkb,
                                                      unsigned short* __restrict__ vT,
                                                      float* __restrict__ Cf,
                                                      int ntileN) {
    __shared__ char lds[131072];
    const int tid = threadIdx.x;
    const int w = tid >> 6, wm = w >> 2, wn = w & 3;
    const int l = tid & 63, c = l & 15, g = l >> 4;
    const int cpx = gridDim.x >> 3;
    const int wg = (blockIdx.x & 7) * cpx + (blockIdx.x >> 3);  // bijective: grid%8==0
    const int tm = wg / ntileN, tn = wg % ntileN;
    const long m0 = (long)tm << 8, n0 = (long)tn << 8;
    const int swg = (g ^ ((c >> 1) & 3)) << 4;          // read-side swizzled chunk byte
    const int ssch = (tid & 3) ^ ((tid >> 3) & 3);      // stage-side source chunk
    const int rb = tid >> 2;

    f32x4 acc[8][4];
#pragma unroll
    for (int i = 0; i < 8; ++i)
#pragma unroll
        for (int j = 0; j < 4; ++j) acc[i][j] = (f32x4){0.f, 0.f, 0.f, 0.f};

#define STG(panel, p0, u, kh, isB) do { \
    char* blk_ = lds + ((isB) ? 65536 : 0) + (((((u) & 1) * 2 + (kh))) << 14); \
    const unsigned short* sp_ = (panel) + (u) * 64 + (kh) * 32 + ssch * 8; \
    async_copy16(sp_ + ((p0) + rb) * 1024L, blk_ + tid * 16); \
    async_copy16(sp_ + ((p0) + 128 + rb) * 1024L, blk_ + 8192 + tid * 16); \
} while (0)

    // prologue: canonical history for steps 0,1 (issue order matters for vmcnt counts)
    STG(Bt, n0, 0, 0, 1); STG(A, m0, 0, 0, 0); STG(Bt, n0, 0, 1, 1); STG(A, m0, 0, 1, 0);
    STG(Bt, n0, 1, 0, 1); STG(A, m0, 1, 0, 0); STG(Bt, n0, 1, 1, 1);
    asm volatile("s_waitcnt vmcnt(10)");
    __builtin_amdgcn_s_barrier();
    __builtin_amdgcn_sched_barrier(0);

#define PHASE_MFMA(IBASE) \
    __builtin_amdgcn_s_setprio(1); \
    _Pragma("unroll") for (int i_ = 0; i_ < 4; ++i_) \
    _Pragma("unroll") for (int j_ = 0; j_ < 4; ++j_) \
        acc[(IBASE) + i_][j_] = __builtin_amdgcn_mfma_f32_16x16x32_bf16(af[i_], bf[j_], acc[(IBASE) + i_][j_], 0, 0, 0); \
    __builtin_amdgcn_s_setprio(0);

#define GSTEP(s, ST1, ST2, ST3, ST4, VMID, VEND) do { \
    const int buf_ = (s) & 1; \
    const char* LA0 = lds + ((buf_ * 2 + 0) << 14); \
    const char* LA1 = lds + ((buf_ * 2 + 1) << 14); \
    const char* LB0 = lds + 65536 + ((buf_ * 2 + 0) << 14); \
    const char* LB1 = lds + 65536 + ((buf_ * 2 + 1) << 14); \
    s16x8 af[4], bf[4]; \
    /* ph1: m-sub 0, k-half 0 */ \
    _Pragma("unroll") for (int i = 0; i < 4; ++i) af[i] = *(const s16x8*)(LA0 + (wm * 128 + i * 16 + c) * 64 + swg); \
    _Pragma("unroll") for (int j = 0; j < 4; ++j) bf[j] = *(const s16x8*)(LB0 + (wn * 64 + j * 16 + c) * 64 + swg); \
    if (ST1) STG(A, m0, (s) + 1, 1, 0); \
    __builtin_amdgcn_s_barrier(); \
    PHASE_MFMA(0) \
    __builtin_amdgcn_s_barrier(); \
    __builtin_amdgcn_sched_barrier(0); \
    /* ph2: m-sub 1, k-half 0 (B regs reused) */ \
    _Pragma("unroll") for (int i = 0; i < 4; ++i) af[i] = *(const s16x8*)(LA0 + (wm * 128 + (4 + i) * 16 + c) * 64 + swg); \
    if (ST2) STG(Bt, n0, (s) + 2, 0, 1); \
    __builtin_amdgcn_s_barrier(); \
    PHASE_MFMA(4) \
    asm volatile("s_waitcnt " VMID); \
    __builtin_amdgcn_s_barrier(); \
    __builtin_amdgcn_sched_barrier(0); \
    /* ph3: m-sub 0, k-half 1 */ \
    _Pragma("unroll") for (int i = 0; i < 4; ++i) af[i] = *(const s16x8*)(LA1 + (wm * 128 + i * 16 + c) * 64 + swg); \
    _Pragma("unroll") for (int j = 0; j < 4; ++j) bf[j] = *(const s16x8*)(LB1 + (wn * 64 + j * 16 + c) * 64 + swg); \
    if (ST3) STG(A, m0, (s) + 2, 0, 0); \
    __builtin_amdgcn_s_barrier(); \
    PHASE_MFMA(0) \
    __builtin_amdgcn_s_barrier(); \
    __builtin_amdgcn_sched_barrier(0); \
    /* ph4: m-sub 1, k-half 1 */ \
    _Pragma("unroll") for (int i = 0; i < 4; ++i) af[i] = *(const s16x8*)(LA1 + (wm * 128 + (4 + i) * 16 + c) * 64 + swg); \
    if (ST4) STG(Bt, n0, (s) + 2, 1, 1); \
    __builtin_amdgcn_s_barrier(); \
    PHASE_MFMA(4) \
    if (VEND) { asm volatile("s_waitcnt " VMID##_E); } \
    __builtin_amdgcn_s_barrier(); \
    __builtin_amdgcn_sched_barrier(0); \
} while (0)

#define VM10 "vmcnt(10)"
#define VM10_E "vmcnt(10)"
#define VM8 "vmcnt(8)"
#define VM8_E "vmcnt(4)"
#define VM0 "vmcnt(0)"
#define VM0_E "vmcnt(0)"

    for (int s = 0; s < 14; ++s) GSTEP(s, 1, 1, 1, 1, VM10, 1);
    GSTEP(14, 1, 0, 0, 0, VM8, 1);
    GSTEP(15, 0, 0, 0, 0, VM0, 0);

    // epilogue
    const long mrow0 = m0 + wm * 128;
    const int ncol0 = (int)n0 + wn * 64;
    if (OM == 0) {
        if (ncol0 < 2048) {
#pragma unroll
            for (int j = 0; j < 4; ++j) {
                int n = ncol0 + j * 16 + c;
                float bv = bias[n];
#pragma unroll
                for (int i = 0; i < 8; ++i)
#pragma unroll
                    for (int r = 0; r < 4; ++r) {
                        long m = mrow0 + i * 16 + 4 * g + r;
                        qkb[m * 2048 + n] = f2b(acc[i][j][r] + bv);
                    }
            }
        } else {
#pragma unroll
            for (int j = 0; j < 4; ++j) {
                int n = ncol0 + j * 16 + c;
                float bv = bias[n];
                int h = (n - 2048) >> 6, hd = n & 63;
#pragma unroll
                for (int i = 0; i < 8; ++i) {
                    long m = mrow0 + i * 16 + 4 * g;
                    long bb = m >> 13, ss = m & 8191;
                    union { unsigned short sh[4]; unsigned long long u; } o;
#pragma unroll
                    for (int r = 0; r < 4; ++r) o.sh[r] = f2b(acc[i][j][r] + bv);
                    *(unsigned long long*)(vT + ((bb * 16 + h) * 64 + hd) * 8192 + ss) = o.u;
                }
            }
        }
    } else {
#pragma unroll
        for (int j = 0; j < 4; ++j) {
            int n = ncol0 + j * 16 + c;
            float bv = bias[n];
#pragma unroll
            for (int i = 0; i < 8; ++i)
#pragma unroll
                for (int r = 0; r < 4; ++r) {
                    long m = mrow0 + i * 16 + 4 * g + r;
                    Cf[m * 1024 + n] = acc[i][j][r] + bv;
                }
        }
    }
#undef STG
#undef PHASE_MFMA
#undef GSTEP
}

// ---------------- ring block attention (QBLK=128: 4 waves x 32 q-rows) ----------------
__global__ __launch_bounds__(256) void attn_kernel(const unsigned short* __restrict__ qkb,
                                                   const unsigned short* __restrict__ vT,
                                                   unsigned short* __restrict__ outp) {
    __shared__ unsigned short Ks[64 * 72];
    __shared__ unsigned short VTs[64 * 72];
    __shared__ unsigned short Pws[4][32 * 72];
    const int bid = blockIdx.x;
    const int wgid = (bid & 7) * 256 + (bid >> 3);
    const int qt = wgid & 3;
    const int nblk = (wgid >> 2) & 15;
    const int h = (wgid >> 6) & 15;
    const int b = wgid >> 10;
    const int tid = threadIdx.x;
    const int w = tid >> 6, l = tid & 63;
    const int c = l & 15, g = l >> 4;

    const long qrow0 = (long)b * 8192 + nblk * 512 + qt * 128 + w * 32 + c;
    s16x8 qf[2][2];
#pragma unroll
    for (int qg = 0; qg < 2; ++qg) {
        const unsigned short* qp = qkb + (qrow0 + qg * 16) * 2048 + h * 64;
        qf[qg][0] = *(const s16x8*)(qp + g * 8);
        qf[qg][1] = *(const s16x8*)(qp + 32 + g * 8);
    }

    char* pw = (char*)(&Pws[w][0]);
    const float C2 = 0.125f * 1.44269504088896f;

    const int cc = tid & 7;
    const int rbase = tid >> 3;
    char* kwp = (char*)Ks + rbase * 144 + cc * 16;
    char* vwp = (char*)VTs + rbase * 144 + cc * 16;

    const int kb1 = (nblk + 1) & 15;
    const unsigned short* Kg0 = qkb + ((long)b * 8192 + nblk * 512) * 2048 + 1024 + h * 64
                                + (long)rbase * 2048 + cc * 8;
    const unsigned short* Kg1 = qkb + ((long)b * 8192 + kb1 * 512) * 2048 + 1024 + h * 64
                                + (long)rbase * 2048 + cc * 8;
    const unsigned short* Vg0 = vT + ((long)(b * 16 + h) * 64 + rbase) * 8192 + nblk * 512 + cc * 8;
    const unsigned short* Vg1 = vT + ((long)(b * 16 + h) * 64 + rbase) * 8192 + kb1 * 512 + cc * 8;

    float outv[2][16];
#pragma unroll
    for (int qg = 0; qg < 2; ++qg)
#pragma unroll
        for (int i = 0; i < 16; ++i) outv[qg][i] = 0.f;

    f32x4 oac[2][4];
#pragma unroll
    for (int qg = 0; qg < 2; ++qg)
#pragma unroll
        for (int i = 0; i < 4; ++i) oac[qg][i] = (f32x4){0.f, 0.f, 0.f, 0.f};
    float mrun[2] = {-3e38f, -3e38f}, lrun[2] = {0.f, 0.f};

    s16x8 kreg0 = *(const s16x8*)(Kg0);
    s16x8 kreg1 = *(const s16x8*)(Kg0 + 32 * 2048);
    s16x8 vreg0 = *(const s16x8*)(Vg0);
    s16x8 vreg1 = *(const s16x8*)(Vg0 + 32 * 8192);

    for (int it = 0; it < 16; ++it) {
        __syncthreads();
        *(s16x8*)(kwp) = kreg0;
        *(s16x8*)(kwp + 32 * 144) = kreg1;
        *(s16x8*)(vwp) = vreg0;
        *(s16x8*)(vwp + 32 * 144) = vreg1;
        {
            int itn = it + 1;
            const unsigned short* kn = ((itn & 8) ? Kg1 : Kg0) + ((itn & 7) << 17);
            const unsigned short* vn = ((itn & 8) ? Vg1 : Vg0) + ((itn & 7) << 6);
            kreg0 = *(const s16x8*)(kn);
            kreg1 = *(const s16x8*)(kn + 32 * 2048);
            vreg0 = *(const s16x8*)(vn);
            vreg1 = *(const s16x8*)(vn + 32 * 8192);
        }
        __syncthreads();

        f32x4 sac[2][4];
#pragma unroll
        for (int qg = 0; qg < 2; ++qg)
#pragma unroll
            for (int i = 0; i < 4; ++i) sac[qg][i] = (f32x4){0.f, 0.f, 0.f, 0.f};
#pragma unroll
        for (int kt = 0; kt < 4; ++kt) {
            const char* kr = (const char*)Ks + (kt * 16 + c) * 144 + g * 16;
            s16x8 a0 = *(const s16x8*)(kr);
            s16x8 a1 = *(const s16x8*)(kr + 64);
            sac[0][kt] = __builtin_amdgcn_mfma_f32_16x16x32_bf16(a0, qf[0][0], sac[0][kt], 0, 0, 0);
            sac[0][kt] = __builtin_amdgcn_mfma_f32_16x16x32_bf16(a1, qf[0][1], sac[0][kt], 0, 0, 0);
            sac[1][kt] = __builtin_amdgcn_mfma_f32_16x16x32_bf16(a0, qf[1][0], sac[1][kt], 0, 0, 0);
            sac[1][kt] = __builtin_amdgcn_mfma_f32_16x16x32_bf16(a1, qf[1][1], sac[1][kt], 0, 0, 0);
        }

#pragma unroll
        for (int qg = 0; qg < 2; ++qg) {
            float mx = sac[qg][0][0];
#pragma unroll
            for (int kt = 0; kt < 4; ++kt)
#pragma unroll
                for (int r = 0; r < 4; ++r) mx = fmaxf(mx, sac[qg][kt][r]);
            mx = fmaxf(mx, __shfl_xor(mx, 16, 64));
            mx = fmaxf(mx, __shfl_xor(mx, 32, 64));
            float mnew = fmaxf(mrun[qg], mx);
            float alpha = exp2f((mrun[qg] - mnew) * C2);
            float ls = 0.f;
#pragma unroll
            for (int kt = 0; kt < 4; ++kt) {
                union { unsigned short sh[4]; unsigned long long u; } pk;
#pragma unroll
                for (int r = 0; r < 4; ++r) {
                    float e = exp2f((sac[qg][kt][r] - mnew) * C2);
                    ls += e;
                    pk.sh[r] = f2b(e);
                }
                *(unsigned long long*)(pw + (qg * 16 + c) * 144 + kt * 32 + g * 8) = pk.u;
            }
            ls += __shfl_xor(ls, 16, 64);
            ls += __shfl_xor(ls, 32, 64);
            lrun[qg] = lrun[qg] * alpha + ls;
            mrun[qg] = mnew;
#pragma unroll
            for (int i = 0; i < 4; ++i) oac[qg][i] *= alpha;
        }

#pragma unroll
        for (int kf = 0; kf < 2; ++kf) {
            s16x8 pf0 = *(const s16x8*)(pw + c * 144 + kf * 64 + g * 16);
            s16x8 pf1 = *(const s16x8*)(pw + (16 + c) * 144 + kf * 64 + g * 16);
#pragma unroll
            for (int ht = 0; ht < 4; ++ht) {
                s16x8 vf = *(const s16x8*)((const char*)VTs + (ht * 16 + c) * 144 + kf * 64 + g * 16);
                oac[0][ht] = __builtin_amdgcn_mfma_f32_16x16x32_bf16(vf, pf0, oac[0][ht], 0, 0, 0);
                oac[1][ht] = __builtin_amdgcn_mfma_f32_16x16x32_bf16(vf, pf1, oac[1][ht], 0, 0, 0);
            }
        }

        if ((it & 7) == 7) {
#pragma unroll
            for (int qg = 0; qg < 2; ++qg) {
                float inv = 1.f / lrun[qg];
#pragma unroll
                for (int i = 0; i < 16; ++i) outv[qg][i] += oac[qg][i >> 2][i & 3] * inv;
#pragma unroll
                for (int i = 0; i < 4; ++i) oac[qg][i] = (f32x4){0.f, 0.f, 0.f, 0.f};
                mrun[qg] = -3e38f;
                lrun[qg] = 0.f;
            }
        }
    }

#pragma unroll
    for (int qg = 0; qg < 2; ++qg) {
        unsigned short* op = outp + (qrow0 + qg * 16) * 1024 + h * 64;
#pragma unroll
        for (int ht = 0; ht < 4; ++ht) {
            union { unsigned short sh[4]; unsigned long long u; } o;
#pragma unroll
            for (int r = 0; r < 4; ++r) o.sh[r] = f2b(outv[qg][ht * 4 + r]);
            *(unsigned long long*)(op + ht * 16 + 4 * g) = o.u;
        }
    }
}

extern "C" void kernel_launch(void* const* d_in, const int* in_sizes, int n_in,
                              void* d_out, int out_size, void* d_ws, size_t ws_size,
                              hipStream_t stream) {
    const float* x    = (const float*)d_in[0];
    const float* Wqkv = (const float*)d_in[1];
    const float* bqkv = (const float*)d_in[2];
    const float* Wout = (const float*)d_in[3];
    const float* bout = (const float*)d_in[4];
    float* out = (float*)d_out;

    char* ws = (char*)d_ws;
    unsigned short* xbf   = (unsigned short*)ws;
    unsigned short* wqkvT = (unsigned short*)(ws + 33554432);
    unsigned short* woutT = (unsigned short*)(ws + 39845888);
    unsigned short* qkb   = (unsigned short*)(ws + 41943040);
    unsigned short* vT    = (unsigned short*)(ws + 109051904);
    unsigned short* attn  = xbf;  // alias: xbf dead after QKV GEMM

    cvt_x_kernel<<<8192, 256, 0, stream>>>(x, xbf);
    cvt_wT_kernel<<<(1024 / 64) * (3072 / 64), 256, 0, stream>>>(Wqkv, wqkvT, 1024, 3072);
    cvt_wT_kernel<<<(1024 / 64) * (1024 / 64), 256, 0, stream>>>(Wout, woutT, 1024, 1024);
    gemm256_kernel<0><<<64 * 12, 512, 0, stream>>>(xbf, wqkvT, bqkv, qkb, vT, nullptr, 12);
    attn_kernel<<<2048, 256, 0, stream>>>(qkb, vT, attn);
    gemm256_kernel<1><<<64 * 4, 512, 0, stream>>>(attn, woutT, bout, nullptr, nullptr, out, 4);
}

// Round 7
// 431.929 us; speedup vs baseline: 1.1602x; 1.0469x over previous
//
#include <hip/hip_runtime.h>
#include <hip/hip_bf16.h>

typedef __attribute__((ext_vector_type(4))) float f32x4;
typedef __attribute__((ext_vector_type(8))) short s16x8;
typedef __attribute__((address_space(3))) unsigned int lds_uint;
typedef __attribute__((address_space(1))) const unsigned int g_uint;

static __device__ __forceinline__ unsigned short f2b(float f) {
    union { __hip_bfloat16 h; unsigned short u; } c;
    c.h = __float2bfloat16(f);
    return c.u;
}

static __device__ __forceinline__ void async_copy16(const void* gsrc, void* ldst) {
    __builtin_amdgcn_global_load_lds((g_uint*)gsrc, (lds_uint*)ldst, 16, 0, 0);
}

// ---------------- x fp32 -> bf16 ----------------
__global__ __launch_bounds__(256) void cvt_x_kernel(const float* __restrict__ x,
                                                    unsigned short* __restrict__ xb) {
    long i = ((long)blockIdx.x * 256 + threadIdx.x) * 8;
    float4 a = *(const float4*)(x + i);
    float4 b = *(const float4*)(x + i + 4);
    union { unsigned short s[8]; s16x8 v; } o;
    o.s[0] = f2b(a.x); o.s[1] = f2b(a.y); o.s[2] = f2b(a.z); o.s[3] = f2b(a.w);
    o.s[4] = f2b(b.x); o.s[5] = f2b(b.y); o.s[6] = f2b(b.z); o.s[7] = f2b(b.w);
    *(s16x8*)(xb + i) = o.v;
}

// ---------------- W [K,N] fp32 -> Wt [N,K] bf16 (transpose+convert) ----------------
__global__ __launch_bounds__(256) void cvt_wT_kernel(const float* __restrict__ W,
                                                     unsigned short* __restrict__ Wt,
                                                     int K, int N) {
    __shared__ float T[64][65];
    int nbk = K >> 6;
    int bk = blockIdx.x % nbk;
    int bn = blockIdx.x / nbk;
    int t = threadIdx.x;
    int r = t >> 4, c4 = (t & 15) << 2;
#pragma unroll
    for (int rd = 0; rd < 4; ++rd) {
        int row = rd * 16 + r;
        float4 v = *(const float4*)(W + (long)(bk * 64 + row) * N + bn * 64 + c4);
        T[row][c4 + 0] = v.x; T[row][c4 + 1] = v.y;
        T[row][c4 + 2] = v.z; T[row][c4 + 3] = v.w;
    }
    __syncthreads();
#pragma unroll
    for (int rd = 0; rd < 4; ++rd) {
        int nrow = rd * 16 + r;
        union { unsigned short s[4]; unsigned long long u; } o;
#pragma unroll
        for (int j = 0; j < 4; ++j) o.s[j] = f2b(T[c4 + j][nrow]);
        *(unsigned long long*)(Wt + (long)(bn * 64 + nrow) * K + bk * 64 + c4) = o.u;
    }
}

// ---------------- 8-phase 256x256 GEMM, K=1024, B^T form ----------------
template<int OM>
__global__ __launch_bounds__(512) void gemm256_kernel(const unsigned short* __restrict__ A,
                                                      const unsigned short* __restrict__ Bt,
                                                      const float* __restrict__ bias,
                                                      unsigned short* __restrict__ qkb,
                                                      unsigned short* __restrict__ vT,
                                                      float* __restrict__ Cf,
                                                      int ntileN) {
    __shared__ char lds[131072];
    const int tid = threadIdx.x;
    const int w = tid >> 6, wm = w >> 2, wn = w & 3;
    const int l = tid & 63, c = l & 15, g = l >> 4;
    const int cpx = gridDim.x >> 3;
    const int wg = (blockIdx.x & 7) * cpx + (blockIdx.x >> 3);  // bijective: grid%8==0
    const int tm = wg / ntileN, tn = wg % ntileN;
    const long m0 = (long)tm << 8, n0 = (long)tn << 8;
    const int swg = (g ^ ((c >> 1) & 3)) << 4;
    const int ssch = (tid & 3) ^ ((tid >> 3) & 3);
    const int rb = tid >> 2;

    f32x4 acc[8][4];
#pragma unroll
    for (int i = 0; i < 8; ++i)
#pragma unroll
        for (int j = 0; j < 4; ++j) acc[i][j] = (f32x4){0.f, 0.f, 0.f, 0.f};

#define STG(panel, p0, u, kh, isB) do { \
    char* blk_ = lds + ((isB) ? 65536 : 0) + (((((u) & 1) * 2 + (kh))) << 14); \
    const unsigned short* sp_ = (panel) + (u) * 64 + (kh) * 32 + ssch * 8; \
    async_copy16(sp_ + ((p0) + rb) * 1024L, blk_ + tid * 16); \
    async_copy16(sp_ + ((p0) + 128 + rb) * 1024L, blk_ + 8192 + tid * 16); \
} while (0)

    STG(Bt, n0, 0, 0, 1); STG(A, m0, 0, 0, 0); STG(Bt, n0, 0, 1, 1); STG(A, m0, 0, 1, 0);
    STG(Bt, n0, 1, 0, 1); STG(A, m0, 1, 0, 0); STG(Bt, n0, 1, 1, 1);
    asm volatile("s_waitcnt vmcnt(10)");
    __builtin_amdgcn_s_barrier();
    __builtin_amdgcn_sched_barrier(0);

#define PHASE_MFMA(IBASE) \
    __builtin_amdgcn_s_setprio(1); \
    _Pragma("unroll") for (int i_ = 0; i_ < 4; ++i_) \
    _Pragma("unroll") for (int j_ = 0; j_ < 4; ++j_) \
        acc[(IBASE) + i_][j_] = __builtin_amdgcn_mfma_f32_16x16x32_bf16(af[i_], bf[j_], acc[(IBASE) + i_][j_], 0, 0, 0); \
    __builtin_amdgcn_s_setprio(0);

#define GSTEP(s, ST1, ST2, ST3, ST4, VMID, VEND) do { \
    const int buf_ = (s) & 1; \
    const char* LA0 = lds + ((buf_ * 2 + 0) << 14); \
    const char* LA1 = lds + ((buf_ * 2 + 1) << 14); \
    const char* LB0 = lds + 65536 + ((buf_ * 2 + 0) << 14); \
    const char* LB1 = lds + 65536 + ((buf_ * 2 + 1) << 14); \
    s16x8 af[4], bf[4]; \
    _Pragma("unroll") for (int i = 0; i < 4; ++i) af[i] = *(const s16x8*)(LA0 + (wm * 128 + i * 16 + c) * 64 + swg); \
    _Pragma("unroll") for (int j = 0; j < 4; ++j) bf[j] = *(const s16x8*)(LB0 + (wn * 64 + j * 16 + c) * 64 + swg); \
    if (ST1) STG(A, m0, (s) + 1, 1, 0); \
    __builtin_amdgcn_s_barrier(); \
    PHASE_MFMA(0) \
    __builtin_amdgcn_s_barrier(); \
    __builtin_amdgcn_sched_barrier(0); \
    _Pragma("unroll") for (int i = 0; i < 4; ++i) af[i] = *(const s16x8*)(LA0 + (wm * 128 + (4 + i) * 16 + c) * 64 + swg); \
    if (ST2) STG(Bt, n0, (s) + 2, 0, 1); \
    __builtin_amdgcn_s_barrier(); \
    PHASE_MFMA(4) \
    asm volatile("s_waitcnt " VMID); \
    __builtin_amdgcn_s_barrier(); \
    __builtin_amdgcn_sched_barrier(0); \
    _Pragma("unroll") for (int i = 0; i < 4; ++i) af[i] = *(const s16x8*)(LA1 + (wm * 128 + i * 16 + c) * 64 + swg); \
    _Pragma("unroll") for (int j = 0; j < 4; ++j) bf[j] = *(const s16x8*)(LB1 + (wn * 64 + j * 16 + c) * 64 + swg); \
    if (ST3) STG(A, m0, (s) + 2, 0, 0); \
    __builtin_amdgcn_s_barrier(); \
    PHASE_MFMA(0) \
    __builtin_amdgcn_s_barrier(); \
    __builtin_amdgcn_sched_barrier(0); \
    _Pragma("unroll") for (int i = 0; i < 4; ++i) af[i] = *(const s16x8*)(LA1 + (wm * 128 + (4 + i) * 16 + c) * 64 + swg); \
    if (ST4) STG(Bt, n0, (s) + 2, 1, 1); \
    __builtin_amdgcn_s_barrier(); \
    PHASE_MFMA(4) \
    if (VEND) { asm volatile("s_waitcnt " VMID##_E); } \
    __builtin_amdgcn_s_barrier(); \
    __builtin_amdgcn_sched_barrier(0); \
} while (0)

#define VM10 "vmcnt(10)"
#define VM10_E "vmcnt(10)"
#define VM8 "vmcnt(8)"
#define VM8_E "vmcnt(4)"
#define VM0 "vmcnt(0)"
#define VM0_E "vmcnt(0)"

    for (int s = 0; s < 14; ++s) GSTEP(s, 1, 1, 1, 1, VM10, 1);
    GSTEP(14, 1, 0, 0, 0, VM8, 1);
    GSTEP(15, 0, 0, 0, 0, VM0, 0);

    const long mrow0 = m0 + wm * 128;
    const int ncol0 = (int)n0 + wn * 64;
    if (OM == 0) {
        if (ncol0 < 2048) {
#pragma unroll
            for (int j = 0; j < 4; ++j) {
                int n = ncol0 + j * 16 + c;
                float bv = bias[n];
#pragma unroll
                for (int i = 0; i < 8; ++i)
#pragma unroll
                    for (int r = 0; r < 4; ++r) {
                        long m = mrow0 + i * 16 + 4 * g + r;
                        qkb[m * 2048 + n] = f2b(acc[i][j][r] + bv);
                    }
            }
        } else {
#pragma unroll
            for (int j = 0; j < 4; ++j) {
                int n = ncol0 + j * 16 + c;
                float bv = bias[n];
                int h = (n - 2048) >> 6, hd = n & 63;
#pragma unroll
                for (int i = 0; i < 8; ++i) {
                    long m = mrow0 + i * 16 + 4 * g;
                    long bb = m >> 13, ss = m & 8191;
                    union { unsigned short sh[4]; unsigned long long u; } o;
#pragma unroll
                    for (int r = 0; r < 4; ++r) o.sh[r] = f2b(acc[i][j][r] + bv);
                    *(unsigned long long*)(vT + ((bb * 16 + h) * 64 + hd) * 8192 + ss) = o.u;
                }
            }
        }
    } else {
#pragma unroll
        for (int j = 0; j < 4; ++j) {
            int n = ncol0 + j * 16 + c;
            float bv = bias[n];
#pragma unroll
            for (int i = 0; i < 8; ++i)
#pragma unroll
                for (int r = 0; r < 4; ++r) {
                    long m = mrow0 + i * 16 + 4 * g + r;
                    Cf[m * 1024 + n] = acc[i][j][r] + bv;
                }
        }
    }
#undef STG
#undef PHASE_MFMA
#undef GSTEP
}

// ---------------- ring block attention (QBLK=128, gload_lds dbuf, counted vmcnt) ----------------
// qkb: [B*S, 2048] bf16 (Q|K); vT: [(b*16+h)*64+hd][8192] bf16; out: [B*S,1024] bf16
__global__ __launch_bounds__(256) void attn_kernel(const unsigned short* __restrict__ qkb,
                                                   const unsigned short* __restrict__ vT,
                                                   unsigned short* __restrict__ outp) {
    // KV[0],KV[1]: K double-buffer; KV[2],KV[3]: V^T double-buffer.
    // Tile layout: [64 rows][8 chunks of 16B]; lds[row][cl] holds global chunk cl ^ (row&7).
    __shared__ __align__(16) char KV[4][8192];
    __shared__ unsigned short Pws[4][32 * 72];  // per-wave P [qg*16+q][key], stride 144B
    const int bid = blockIdx.x;
    const int wgid = (bid & 7) * 256 + (bid >> 3);  // XCD swizzle (2048 wgs)
    const int qt = wgid & 3;
    const int nblk = (wgid >> 2) & 15;
    const int h = (wgid >> 6) & 15;
    const int b = wgid >> 10;
    const int tid = threadIdx.x;
    const int w = tid >> 6, l = tid & 63;
    const int c = l & 15, g = l >> 4;

    const long qrow0 = (long)b * 8192 + nblk * 512 + qt * 128 + w * 32 + c;
    s16x8 qf[2][2];
#pragma unroll
    for (int qg = 0; qg < 2; ++qg) {
        const unsigned short* qp = qkb + (qrow0 + qg * 16) * 2048 + h * 64;
        qf[qg][0] = *(const s16x8*)(qp + g * 8);
        qf[qg][1] = *(const s16x8*)(qp + 32 + g * 8);
    }

    char* pw = (char*)(&Pws[w][0]);
    const float C2 = 0.125f * 1.44269504088896f;  // scale * log2(e)

    // staging coords: each thread copies rows rw and rw+32, 16B chunk cl (source chunk XOR-swizzled)
    const int cl = tid & 7, rw = tid >> 3;
    const int sc = cl ^ (rw & 7);
    const int kb1 = (nblk + 1) & 15;
    const unsigned short* Kg0 = qkb + ((long)b * 8192 + nblk * 512 + rw) * 2048 + 1024 + h * 64 + sc * 8;
    const unsigned short* Kg1 = qkb + ((long)b * 8192 + kb1 * 512 + rw) * 2048 + 1024 + h * 64 + sc * 8;
    const unsigned short* Vg0 = vT + ((long)(b * 16 + h) * 64 + rw) * 8192 + nblk * 512 + sc * 8;
    const unsigned short* Vg1 = vT + ((long)(b * 16 + h) * 64 + rw) * 8192 + kb1 * 512 + sc * 8;

#define STAGE(tile) do { \
    const unsigned short* kn_ = (((tile) & 8) ? Kg1 : Kg0) + ((long)((tile) & 7) << 17); \
    const unsigned short* vn_ = (((tile) & 8) ? Vg1 : Vg0) + (((tile) & 7) << 6); \
    char* kd_ = KV[(tile) & 1] + tid * 16; \
    char* vd_ = KV[2 + ((tile) & 1)] + tid * 16; \
    async_copy16(kn_, kd_); \
    async_copy16(kn_ + 32L * 2048, kd_ + 4096); \
    async_copy16(vn_, vd_); \
    async_copy16(vn_ + 32L * 8192, vd_ + 4096); \
} while (0)

    float outv[2][16];
#pragma unroll
    for (int qg = 0; qg < 2; ++qg)
#pragma unroll
        for (int i = 0; i < 16; ++i) outv[qg][i] = 0.f;
    f32x4 oac[2][4];
#pragma unroll
    for (int qg = 0; qg < 2; ++qg)
#pragma unroll
        for (int i = 0; i < 4; ++i) oac[qg][i] = (f32x4){0.f, 0.f, 0.f, 0.f};
    float mrun[2] = {-3e38f, -3e38f}, lrun[2] = {0.f, 0.f};  // lrun is per-lane partial

    const int ch0 = (g ^ (c & 7)) << 4;  // swizzled byte offset of chunk g in row (..+c)

    STAGE(0);

    for (int it = 0; it < 16; ++it) {
        if (it < 15) {
            STAGE(it + 1);
            asm volatile("s_waitcnt vmcnt(4)" ::: "memory");
        } else {
            asm volatile("s_waitcnt vmcnt(0)" ::: "memory");
        }
        __builtin_amdgcn_s_barrier();
        __builtin_amdgcn_sched_barrier(0);

        const char* Kc = KV[it & 1];
        const char* Vc = KV[2 + (it & 1)];

        // S^T = K @ Q^T : lane (c,g) holds S^T[key = kt*16 + 4g + r][q = c] per qg
        f32x4 sac[2][4];
#pragma unroll
        for (int qg = 0; qg < 2; ++qg)
#pragma unroll
            for (int i = 0; i < 4; ++i) sac[qg][i] = (f32x4){0.f, 0.f, 0.f, 0.f};
        __builtin_amdgcn_s_setprio(1);
#pragma unroll
        for (int kt = 0; kt < 4; ++kt) {
            const char* kr = Kc + (kt * 16 + c) * 128;
            s16x8 a0 = *(const s16x8*)(kr + ch0);
            s16x8 a1 = *(const s16x8*)(kr + (ch0 ^ 64));
            sac[0][kt] = __builtin_amdgcn_mfma_f32_16x16x32_bf16(a0, qf[0][0], sac[0][kt], 0, 0, 0);
            sac[0][kt] = __builtin_amdgcn_mfma_f32_16x16x32_bf16(a1, qf[0][1], sac[0][kt], 0, 0, 0);
            sac[1][kt] = __builtin_amdgcn_mfma_f32_16x16x32_bf16(a0, qf[1][0], sac[1][kt], 0, 0, 0);
            sac[1][kt] = __builtin_amdgcn_mfma_f32_16x16x32_bf16(a1, qf[1][1], sac[1][kt], 0, 0, 0);
        }
        __builtin_amdgcn_s_setprio(0);

        // online softmax per q-group (q = c); keys spread over g-lanes and regs
#pragma unroll
        for (int qg = 0; qg < 2; ++qg) {
            float mx = sac[qg][0][0];
#pragma unroll
            for (int kt = 0; kt < 4; ++kt)
#pragma unroll
                for (int r = 0; r < 4; ++r) mx = fmaxf(mx, sac[qg][kt][r]);
            mx = fmaxf(mx, __shfl_xor(mx, 16, 64));
            mx = fmaxf(mx, __shfl_xor(mx, 32, 64));
            float mnew = fmaxf(mrun[qg], mx);
            float alpha = exp2f((mrun[qg] - mnew) * C2);
            float ls = 0.f;
#pragma unroll
            for (int kt = 0; kt < 4; ++kt) {
                union { unsigned short sh[4]; unsigned long long u; } pk;
#pragma unroll
                for (int r = 0; r < 4; ++r) {
                    float e = exp2f((sac[qg][kt][r] - mnew) * C2);
                    ls += e;
                    pk.sh[r] = f2b(e);
                }
                *(unsigned long long*)(pw + (qg * 16 + c) * 144 + kt * 32 + g * 8) = pk.u;
            }
            lrun[qg] = lrun[qg] * alpha + ls;  // per-lane partial; reduced at pass end
            mrun[qg] = mnew;
#pragma unroll
            for (int i = 0; i < 4; ++i) oac[qg][i] *= alpha;
        }

        // O^T += V^T @ P^T
        __builtin_amdgcn_s_setprio(1);
#pragma unroll
        for (int kf = 0; kf < 2; ++kf) {
            s16x8 pf0 = *(const s16x8*)(pw + c * 144 + kf * 64 + g * 16);
            s16x8 pf1 = *(const s16x8*)(pw + (16 + c) * 144 + kf * 64 + g * 16);
#pragma unroll
            for (int ht = 0; ht < 4; ++ht) {
                s16x8 vf = *(const s16x8*)(Vc + (ht * 16 + c) * 128 + (ch0 ^ (kf << 6)));
                oac[0][ht] = __builtin_amdgcn_mfma_f32_16x16x32_bf16(vf, pf0, oac[0][ht], 0, 0, 0);
                oac[1][ht] = __builtin_amdgcn_mfma_f32_16x16x32_bf16(vf, pf1, oac[1][ht], 0, 0, 0);
            }
        }
        __builtin_amdgcn_s_setprio(0);

        if ((it & 7) == 7) {  // pass boundary: reduce lrun, fold normalized result
#pragma unroll
            for (int qg = 0; qg < 2; ++qg) {
                float lt = lrun[qg];
                lt += __shfl_xor(lt, 16, 64);
                lt += __shfl_xor(lt, 32, 64);
                float inv = 1.f / lt;
#pragma unroll
                for (int i = 0; i < 16; ++i) outv[qg][i] += oac[qg][i >> 2][i & 3] * inv;
#pragma unroll
                for (int i = 0; i < 4; ++i) oac[qg][i] = (f32x4){0.f, 0.f, 0.f, 0.f};
                mrun[qg] = -3e38f;
                lrun[qg] = 0.f;
            }
        }
        __builtin_amdgcn_sched_barrier(0);
        __builtin_amdgcn_s_barrier();  // all waves done reading buf[it&1]; it may be overwritten next iter
        __builtin_amdgcn_sched_barrier(0);
    }
#undef STAGE

    // lane holds O^T[hd = ht*16 + 4g + r][q = c] per qg; 8B packed stores
#pragma unroll
    for (int qg = 0; qg < 2; ++qg) {
        unsigned short* op = outp + (qrow0 + qg * 16) * 1024 + h * 64;
#pragma unroll
        for (int ht = 0; ht < 4; ++ht) {
            union { unsigned short sh[4]; unsigned long long u; } o;
#pragma unroll
            for (int r = 0; r < 4; ++r) o.sh[r] = f2b(outv[qg][ht * 4 + r]);
            *(unsigned long long*)(op + ht * 16 + 4 * g) = o.u;
        }
    }
}

extern "C" void kernel_launch(void* const* d_in, const int* in_sizes, int n_in,
                              void* d_out, int out_size, void* d_ws, size_t ws_size,
                              hipStream_t stream) {
    const float* x    = (const float*)d_in[0];
    const float* Wqkv = (const float*)d_in[1];
    const float* bqkv = (const float*)d_in[2];
    const float* Wout = (const float*)d_in[3];
    const float* bout = (const float*)d_in[4];
    float* out = (float*)d_out;

    char* ws = (char*)d_ws;
    unsigned short* xbf   = (unsigned short*)ws;
    unsigned short* wqkvT = (unsigned short*)(ws + 33554432);
    unsigned short* woutT = (unsigned short*)(ws + 39845888);
    unsigned short* qkb   = (unsigned short*)(ws + 41943040);
    unsigned short* vT    = (unsigned short*)(ws + 109051904);
    unsigned short* attn  = xbf;  // alias: xbf dead after QKV GEMM

    cvt_x_kernel<<<8192, 256, 0, stream>>>(x, xbf);
    cvt_wT_kernel<<<(1024 / 64) * (3072 / 64), 256, 0, stream>>>(Wqkv, wqkvT, 1024, 3072);
    cvt_wT_kernel<<<(1024 / 64) * (1024 / 64), 256, 0, stream>>>(Wout, woutT, 1024, 1024);
    gemm256_kernel<0><<<64 * 12, 512, 0, stream>>>(xbf, wqkvT, bqkv, qkb, vT, nullptr, 12);
    attn_kernel<<<2048, 256, 0, stream>>>(qkb, vT, attn);
    gemm256_kernel<1><<<64 * 4, 512, 0, stream>>>(attn, woutT, bout, nullptr, nullptr, out, 4);
}